// Round 13
// baseline (1207.097 us; speedup 1.0000x reference)
//
#include <hip/hip_runtime.h>
#include <stdint.h>

#define TT 16

typedef float v2f __attribute__((ext_vector_type(2)));

// Locked reference semantics (verified absmax=0.0 in R9/R10/R12):
//   cur1 = fmaf(x2,w2, fmaf(x1,w1, x0*w0)) + b1          (f32, fma ascending)
//   mem  = fmaf(0.9f, mem, cur) - reset                  (fused recurrence)
//   dots = single-acc ascending-h masked adds, bias added after dot
// Exact rewrites: masked add == fma(m,w,acc), m in {0,1} (acc never -0);
// float2 pk-fma componentwise IEEE; VGPR spike bits + readlane.
// Inner loop = R9's proven VALU-mask form (v_bfe+v_cvt amortized over 2
// pk_fma). R12 lesson: SGPR cselect masks are SALU-bound (1 SALU/cyc vs
// 2 VALU/cyc per CU) — don't. R11 lesson: per-bit branches spill accs.
// R13 change vs R9: loads + readlanes hoisted UNCONDITIONALLY above the row
// branches and software-prefetched one h4-group ahead, so L2-hit latency is
// covered by the previous group's fma burst instead of stalling at use.
// READLANE LEGALITY (R8): readlanes + source defs in uniform flow only;
// final store is the only divergent code.
__device__ __forceinline__ float lstep(float mem, float cur) {
    const float reset = (mem > 1.0f) ? 1.0f : 0.0f;
    return __builtin_fmaf(0.9f, mem, cur) - reset;
}

__global__ __launch_bounds__(256, 4) void snn_fast(
    const float* __restrict__ x,     // [B,3]
    const float* __restrict__ W1,    // [3,256]
    const float* __restrict__ b1,    // [256]
    const float* __restrict__ W2,    // [256,256]
    const float* __restrict__ b2,    // [256]
    const float* __restrict__ Wout,  // [25,256,4]
    const float* __restrict__ bout,  // [25,4]
    float* __restrict__ out)         // [B,25,4]
{
#pragma clang fp contract(off)
    const int tid = threadIdx.x;
    const int l   = tid & 63;                 // lane; owns hidden units 4l..4l+3
    const int b   = blockIdx.x * 4 + (tid >> 6);

    // ---------------- Phase A: layer 1 ----------------
    const float x0 = x[b * 3 + 0], x1 = x[b * 3 + 1], x2 = x[b * 3 + 2];
    const float4 w1r0 = ((const float4*)W1)[l];
    const float4 w1r1 = ((const float4*)W1)[64 + l];
    const float4 w1r2 = ((const float4*)W1)[128 + l];
    const float4 b1v  = ((const float4*)b1)[l];

    const float wa0[4] = {w1r0.x, w1r0.y, w1r0.z, w1r0.w};
    const float wa1[4] = {w1r1.x, w1r1.y, w1r1.z, w1r1.w};
    const float wa2[4] = {w1r2.x, w1r2.y, w1r2.z, w1r2.w};
    const float bb1[4] = {b1v.x, b1v.y, b1v.z, b1v.w};

    uint32_t b1r[4];   // spike bits for h = 4l+i (VGPRs, uniform flow)
#pragma unroll
    for (int i = 0; i < 4; ++i) {
        const float cur = fmaf(x2, wa2[i], fmaf(x1, wa1[i], x0 * wa0[i])) + bb1[i];
        float mem = 0.f; uint32_t p = 0;
#pragma unroll
        for (int t = 0; t < TT; ++t) {
            mem = lstep(mem, cur);
            if (mem > 1.0f) p |= (1u << t);
        }
        b1r[i] = p;
    }

    // ------- Phase B: layer 2 — R9 inner loop + hoisted prefetched loads -----
    v2f acc0[TT], acc1[TT];   // acc0: j=4l,4l+1  acc1: j=4l+2,4l+3
#pragma unroll
    for (int t = 0; t < TT; ++t) { acc0[t] = (v2f)0.f; acc1[t] = (v2f)0.f; }

    const float4* W2v = (const float4*)W2;
    float4   wcur[4];
    uint32_t pcur[4];
#pragma unroll
    for (int c = 0; c < 4; ++c) {
        wcur[c] = W2v[c * 64 + l];                           // group 0
        pcur[c] = (uint32_t)__builtin_amdgcn_readlane((int)b1r[c], 0);
    }
    for (int h4 = 0; h4 < 64; ++h4) {
        const int hn = (h4 < 63) ? (h4 + 1) : 63;            // s_min, no branch
        float4   wnxt[4];
        uint32_t pnxt[4];
#pragma unroll
        for (int c = 0; c < 4; ++c) {
            wnxt[c] = W2v[(hn * 4 + c) * 64 + l];            // prefetch next grp
            pnxt[c] = (uint32_t)__builtin_amdgcn_readlane((int)b1r[c], hn);
        }
#pragma unroll
        for (int c = 0; c < 4; ++c) {
            const uint32_t p = pcur[c];
            if (p) {                              // uniform row skip
                const v2f w01 = {wcur[c].x, wcur[c].y};
                const v2f w23 = {wcur[c].z, wcur[c].w};
#pragma unroll
                for (int t = 0; t < TT; ++t) {
                    const float m = (float)((p >> t) & 1u);  // v_bfe + v_cvt
                    const v2f mm = {m, m};
                    acc0[t] = __builtin_elementwise_fma(mm, w01, acc0[t]);
                    acc1[t] = __builtin_elementwise_fma(mm, w23, acc1[t]);
                }
            }
        }
#pragma unroll
        for (int c = 0; c < 4; ++c) { wcur[c] = wnxt[c]; pcur[c] = pnxt[c]; }
    }

    const float4 b2v = ((const float4*)b2)[l];
    const float b2a[4] = {b2v.x, b2v.y, b2v.z, b2v.w};
    uint32_t b2r[4];
#pragma unroll
    for (int i = 0; i < 4; ++i) {
        float mem = 0.f; uint32_t p = 0;
#pragma unroll
        for (int t = 0; t < TT; ++t) {
            const float a = (i < 2) ? ((i == 0) ? acc0[t].x : acc0[t].y)
                                    : ((i == 2) ? acc1[t].x : acc1[t].y);
            const float cur = a + b2a[i];         // dot + bias, bias last
            mem = lstep(mem, cur);
            if (mem > 1.0f) p |= (1u << t);
        }
        b2r[i] = p;
    }

    // ------- Phase C: output layer — ALL 64 lanes run (uniform flow) ---------
    const int oc1 = l;                            // 0..63 (<100)
    const int oc2 = (l < 50) ? (l + 50) : 99;     // clamp lanes 50..63 (dup)
    const int base1 = (oc1 >> 2) * 1024 + (oc1 & 3);
    const int base2 = (oc2 >> 2) * 1024 + (oc2 & 3);

    v2f acco[TT];
#pragma unroll
    for (int t = 0; t < TT; ++t) acco[t] = (v2f)0.f;

    v2f      ocur[4];
    uint32_t qcur[4];
#pragma unroll
    for (int c = 0; c < 4; ++c) {
        ocur[c] = v2f{Wout[base1 + c * 4], Wout[base2 + c * 4]};
        qcur[c] = (uint32_t)__builtin_amdgcn_readlane((int)b2r[c], 0);
    }
    for (int h4 = 0; h4 < 64; ++h4) {
        const int hn = (h4 < 63) ? (h4 + 1) : 63;
        v2f      onxt[4];
        uint32_t qnxt[4];
#pragma unroll
        for (int c = 0; c < 4; ++c) {
            const int h = hn * 4 + c;
            onxt[c] = v2f{Wout[base1 + h * 4], Wout[base2 + h * 4]};
            qnxt[c] = (uint32_t)__builtin_amdgcn_readlane((int)b2r[c], hn);
        }
#pragma unroll
        for (int c = 0; c < 4; ++c) {
            const uint32_t p = qcur[c];
            if (p) {
#pragma unroll
                for (int t = 0; t < TT; ++t) {
                    const float m = (float)((p >> t) & 1u);
                    const v2f mm = {m, m};
                    acco[t] = __builtin_elementwise_fma(mm, ocur[c], acco[t]);
                }
            }
        }
#pragma unroll
        for (int c = 0; c < 4; ++c) { ocur[c] = onxt[c]; qcur[c] = qnxt[c]; }
    }

    const float bo1 = bout[oc1], bo2 = bout[oc2];
    float memA = 0.f, memB = 0.f;
    int cntA = 0, cntB = 0;
#pragma unroll
    for (int t = 0; t < TT; ++t) {
        const float curA = acco[t].x + bo1;
        const float curB = acco[t].y + bo2;
        memA = lstep(memA, curA);
        memB = lstep(memB, curB);
        if (memA > 1.0f) ++cntA;
        if (memB > 1.0f) ++cntB;
    }
    if (l < 50) {
        out[b * 100 + oc1] = (float)cntA;
        out[b * 100 + oc2] = (float)cntB;
    }
}

extern "C" void kernel_launch(void* const* d_in, const int* in_sizes, int n_in,
                              void* d_out, int out_size, void* d_ws, size_t ws_size,
                              hipStream_t stream) {
    const float* x    = (const float*)d_in[0];
    const float* W1   = (const float*)d_in[1];
    const float* b1   = (const float*)d_in[2];
    const float* W2   = (const float*)d_in[3];
    const float* b2   = (const float*)d_in[4];
    const float* Wout = (const float*)d_in[5];
    const float* bout = (const float*)d_in[6];
    float* out = (float*)d_out;

    const int B = in_sizes[0] / 3;   // 32768
    snn_fast<<<B / 4, 256, 0, stream>>>(x, W1, b1, W2, b2, Wout, bout, out);
}